// Round 2
// baseline (368.432 us; speedup 1.0000x reference)
//
#include <hip/hip_runtime.h>
#include <math.h>

namespace {

constexpr int kB   = 64;
constexpr int kCin = 8;
constexpr int kR   = 800;
constexpr int kNC  = 128;
constexpr int kO   = 16;
constexpr int CT   = 256;   // conversion kernel TPB
constexpr int MT   = 512;   // main kernel TPB
constexpr int NITER = 3;
constexpr size_t WS_NEEDED =
    (size_t)kNC * kO * kR * kCin * sizeof(unsigned short);  // 26,214,400 B

typedef _Float16 half2v __attribute__((ext_vector_type(2)));

__device__ __forceinline__ half2v u2h(unsigned int u) {
  union { unsigned int u; half2v h; } x;
  x.u = u;
  return x.h;
}

__device__ __forceinline__ unsigned short f2h(float f) {
  union { _Float16 h; unsigned short s; } x;
  x.h = (_Float16)f;
  return x.s;
}

// DPP adds: xor1 = quad_perm{1,0,3,2}=0xB1, xor2 = quad_perm{2,3,0,1}=0x4E,
// mir8 = row_half_mirror (0x141): lane i <-> 7-i within each 8-lane half-row.
// After xor1+xor2 (quad sums), mir8 adds the sibling quad -> 8-lane total.
__device__ __forceinline__ float dpp_xor1_add(float v) {
  const int o = __builtin_amdgcn_mov_dpp(__float_as_int(v), 0xB1, 0xF, 0xF, true);
  return v + __int_as_float(o);
}
__device__ __forceinline__ float dpp_xor2_add(float v) {
  const int o = __builtin_amdgcn_mov_dpp(__float_as_int(v), 0x4E, 0xF, 0xF, true);
  return v + __int_as_float(o);
}
__device__ __forceinline__ float dpp_mir8_add(float v) {
  const int o = __builtin_amdgcn_mov_dpp(__float_as_int(v), 0x141, 0xF, 0xF, true);
  return v + __int_as_float(o);
}

// ---- W conversion: fp32 [c][r][i][o] -> fp16 [c][o][r][i] (uint4 = 8 i's) --
// Streaming 32-row tiles: 16.9 KB LDS -> 8 blocks/CU, 3200 blocks.
__global__ __launch_bounds__(CT) void conv_w(const float* __restrict__ W,
                                             unsigned short* __restrict__ Wb) {
  __shared__ float tile[32 * 132];   // 32 r-rows x 128 cols (+4 pad)
  const int blk = blockIdx.x;        // c*25 + rt
  const int c  = blk / 25;
  const int rt = blk - c * 25;
  const int r0 = rt * 32;
  const int t  = threadIdx.x;

  const float4* src =
      reinterpret_cast<const float4*>(W + ((size_t)c * kR + r0) * kCin * kO);
  #pragma unroll
  for (int k2 = 0; k2 < 4; ++k2) {
    const int i4  = t + k2 * CT;
    const float4 v = src[i4];
    const int fi = i4 * 4, row = fi >> 7, pos = fi & 127;
    *reinterpret_cast<float4*>(&tile[row * 132 + pos]) = v;
  }
  __syncthreads();

  const int o = t >> 4;
  #pragma unroll
  for (int k2 = 0; k2 < 2; ++k2) {
    const int rl = (t & 15) + 16 * k2;
    unsigned int pk[4];
    #pragma unroll
    for (int q = 0; q < 4; ++q) {
      const unsigned int lo = f2h(tile[rl * 132 + (2 * q + 0) * 16 + o]);
      const unsigned int hi = f2h(tile[rl * 132 + (2 * q + 1) * 16 + o]);
      pk[q] = lo | (hi << 16);
    }
    reinterpret_cast<uint4*>(Wb)[(size_t)(c * kO + o) * kR + (r0 + rl)] =
        make_uint4(pk[0], pk[1], pk[2], pk[3]);
  }
}

// Per-row prior computation for TWO batches sharing one W load stream.
__device__ __forceinline__ void row_priors(const uint4* __restrict__ Wc,
                                           const float* __restrict__ xb0,
                                           const float* __restrict__ xb1,
                                           int r,
                                           half2v* __restrict__ Pa,
                                           half2v* __restrict__ Pb) {
  half2v xa[4], xc[4];
  #pragma unroll
  for (int q = 0; q < 4; ++q) {
    xa[q] = half2v{(_Float16)xb0[(2*q) * kR + r], (_Float16)xb0[(2*q+1) * kR + r]};
    xc[q] = half2v{(_Float16)xb1[(2*q) * kR + r], (_Float16)xb1[(2*q+1) * kR + r]};
  }
  #pragma unroll
  for (int ob = 0; ob < 2; ++ob) {
    uint4 w[8];
    #pragma unroll
    for (int u = 0; u < 8; ++u) w[u] = Wc[(size_t)(ob * 8 + u) * kR + r];
    float pa[8], pb[8];
    #pragma unroll
    for (int u = 0; u < 8; ++u) {
      float a = __builtin_amdgcn_fdot2(u2h(w[u].x), xa[0], 0.f, false);
      a = __builtin_amdgcn_fdot2(u2h(w[u].y), xa[1], a, false);
      a = __builtin_amdgcn_fdot2(u2h(w[u].z), xa[2], a, false);
      a = __builtin_amdgcn_fdot2(u2h(w[u].w), xa[3], a, false);
      pa[u] = a;
      float bb = __builtin_amdgcn_fdot2(u2h(w[u].x), xc[0], 0.f, false);
      bb = __builtin_amdgcn_fdot2(u2h(w[u].y), xc[1], bb, false);
      bb = __builtin_amdgcn_fdot2(u2h(w[u].z), xc[2], bb, false);
      bb = __builtin_amdgcn_fdot2(u2h(w[u].w), xc[3], bb, false);
      pb[u] = bb;
    }
    #pragma unroll
    for (int q = 0; q < 4; ++q) {
      Pa[ob * 4 + q] = half2v{(_Float16)pa[2*q], (_Float16)pa[2*q+1]};
      Pb[ob * 4 + q] = half2v{(_Float16)pb[2*q], (_Float16)pb[2*q+1]};
    }
  }
}

// ---- main: 2-way b-batching. Block = (c, b-pair). Each W uint4 load feeds
// fdot2 for BOTH b's -> W L2 traffic halved. Phase 2 runs both b's
// concurrently (shared barriers, 2x active lanes in reductions) with the
// merged stage-2/3 reduction (col-major partials + 8-lane DPP): 6 barriers
// per block instead of 9 per (c,b) before. Priors stay PACKED fp16 (R1
// lesson: fp32 P starved the load pipeline of registers). ----
__global__ __launch_bounds__(MT, 4) void caps_route(
    const float* __restrict__ x, const unsigned short* __restrict__ Wb,
    float* __restrict__ out) {
  constexpr int RST = 20;                 // 17 cols + 3 pad
  __shared__ float red[2 * 128 * RST];    // 20.5 KB (b0: rows 0-127, b1: 128-255)
  __shared__ float shs[2 * RST];

  const int t = threadIdx.x;
  // XCD swizzle: 16 c's per XCD -> fp16 W working set 3.3 MB < 4 MB L2.
  const int j   = blockIdx.x;
  const int xcd = j & 7;
  const int kk  = j >> 3;                 // 0..511
  const int c   = ((kk >> 5) << 3) + xcd; // 0..127
  const int bp  = kk & 31;                // 0..31
  const int b0  = 2 * bp, b1 = b0 + 1;

  const float* xb0 = x + (size_t)b0 * kCin * kR;
  const float* xb1 = x + (size_t)b1 * kCin * kR;
  const bool  has2 = (t < kR - MT);       // t < 288 owns second row r2
  const int   r1   = t, r2 = MT + t;

  // Packed priors: P{batch}{row}[8] half2v (16 o's each) = 32 VGPR total.
  half2v P00[8], P01[8], P10[8], P11[8];
  #pragma unroll
  for (int q = 0; q < 8; ++q) {
    P01[q] = half2v{(_Float16)0.f, (_Float16)0.f};
    P11[q] = half2v{(_Float16)0.f, (_Float16)0.f};
  }

  const uint4* Wc = reinterpret_cast<const uint4*>(Wb) + (size_t)c * kO * kR;

  row_priors(Wc, xb0, xb1, r1, P00, P10);
  if (has2) row_priors(Wc, xb0, xb1, r2, P01, P11);

  // -------- Phase 2: 3 routing iterations, both b's concurrent ------------
  float l00 = 0.f, l01 = 0.f, l10 = 0.f, l11 = 0.f;  // l{b}{row}
  #pragma unroll
  for (int it = 0; it < NITER; ++it) {
    const float e00 = (it == 0) ? 1.f : __expf(l00);
    const float e01 = has2 ? ((it == 0) ? 1.f : __expf(l01)) : 0.f;
    const float e10 = (it == 0) ? 1.f : __expf(l10);
    const float e11 = has2 ? ((it == 0) ? 1.f : __expf(l11)) : 0.f;

    float sp0[kO + 1], sp1[kO + 1];
    sp0[kO] = e00 + e01;
    sp1[kO] = e10 + e11;
    #pragma unroll
    for (int q = 0; q < 8; ++q) {
      sp0[2*q]   = e00 * (float)P00[q].x + e01 * (float)P01[q].x;
      sp0[2*q+1] = e00 * (float)P00[q].y + e01 * (float)P01[q].y;
      sp1[2*q]   = e10 * (float)P10[q].x + e11 * (float)P11[q].x;
      sp1[2*q+1] = e10 * (float)P10[q].y + e11 * (float)P11[q].y;
    }

    #pragma unroll
    for (int v = 0; v <= kO; ++v) { sp0[v] = dpp_xor1_add(sp0[v]); sp1[v] = dpp_xor1_add(sp1[v]); }
    #pragma unroll
    for (int v = 0; v <= kO; ++v) { sp0[v] = dpp_xor2_add(sp0[v]); sp1[v] = dpp_xor2_add(sp1[v]); }

    if ((t & 3) == 0) {
      float* ra = &red[(t >> 2) * RST];
      float* rb = &red[(128 + (t >> 2)) * RST];
      #pragma unroll
      for (int q = 0; q < 4; ++q) {
        *reinterpret_cast<float4*>(ra + 4 * q) =
            make_float4(sp0[4*q], sp0[4*q+1], sp0[4*q+2], sp0[4*q+3]);
        *reinterpret_cast<float4*>(rb + 4 * q) =
            make_float4(sp1[4*q], sp1[4*q+1], sp1[4*q+2], sp1[4*q+3]);
      }
      ra[16] = sp0[16];
      rb[16] = sp1[16];
    }
    __syncthreads();

    // Merged stage 2+3: t<136 handles b0, t in [256,392) handles b1.
    // tt = col*8+q: 8-lane DPP group (fixed col) sums the 8 q-partials.
    if (t < 136 || (t >= 256 && t < 392)) {
      const int bsel = t >> 8;            // 0 or 1
      const int tt   = t & 255;           // 0..135
      const int q    = tt & 7, col = tt >> 3;
      const float* base = &red[bsel * 128 * RST];
      float a = 0.f;
      #pragma unroll
      for (int rr = 0; rr < 16; ++rr) a += base[(rr * 8 + q) * RST + col];
      a = dpp_xor1_add(a);
      a = dpp_xor2_add(a);
      a = dpp_mir8_add(a);
      if (q == 0) shs[bsel * RST + col] = a;
    }
    __syncthreads();

    const float Z0i = 1.f / shs[kO];
    const float Z1i = 1.f / shs[RST + kO];
    float ss0 = 0.f, ss1 = 0.f;
    #pragma unroll
    for (int o = 0; o < kO; ++o) {
      ss0 += shs[o] * shs[o];
      ss1 += shs[RST + o] * shs[RST + o];
    }
    const float sn0 = ss0 * Z0i * Z0i;
    const float g0  = Z0i * sqrtf(sn0) / (1.f + sn0);
    const float sn1 = ss1 * Z1i * Z1i;
    const float g1  = Z1i * sqrtf(sn1) / (1.f + sn1);

    if (it < NITER - 1) {
      float d00 = 0.f, d01 = 0.f, d10 = 0.f, d11 = 0.f;
      #pragma unroll
      for (int q = 0; q < 8; ++q) {
        const float s0a = shs[2*q], s0b = shs[2*q+1];
        const float s1a = shs[RST + 2*q], s1b = shs[RST + 2*q+1];
        d00 += (float)P00[q].x * s0a + (float)P00[q].y * s0b;
        d01 += (float)P01[q].x * s0a + (float)P01[q].y * s0b;
        d10 += (float)P10[q].x * s1a + (float)P10[q].y * s1b;
        d11 += (float)P11[q].x * s1a + (float)P11[q].y * s1b;
      }
      l00 += d00 * g0;
      if (has2) l01 += d01 * g0;
      l10 += d10 * g1;
      if (has2) l11 += d11 * g1;
    } else {
      if (t < kO) {
        out[(size_t)b0 * kO * kNC + t * kNC + c] = shs[t] * g0;
      } else if (t >= 256 && t < 256 + kO) {
        const int o = t - 256;
        out[(size_t)b1 * kO * kNC + o * kNC + c] = shs[RST + o] * g1;
      }
    }
  }
}

// ---- fallback (no workspace): fp32 W direct, single-b blocks -------------
__global__ __launch_bounds__(MT, 4) void caps_route_f32(
    const float* __restrict__ x, const float* __restrict__ W,
    float* __restrict__ out) {
  constexpr int RST = 20;
  __shared__ float red[128 * RST];
  __shared__ float red2[8 * RST];
  __shared__ float shs[RST];

  const int t   = threadIdx.x;
  const int j   = blockIdx.x;
  const int xcd = j & 7;
  const int kk  = j >> 3;
  const int c   = ((kk >> 6) << 3) + xcd;
  const int b   = kk & 63;

  const float* xb  = x + (size_t)b * kCin * kR;
  const bool  has2 = (t < kR - MT);
  const int   r1   = t, r2 = MT + t;

  float P1[kO], P2[kO];
  #pragma unroll
  for (int o = 0; o < kO; ++o) P2[o] = 0.f;
  {
    float xa[kCin];
    #pragma unroll
    for (int i = 0; i < kCin; ++i) xa[i] = xb[i * kR + r1];
    const float* Wc = W + ((size_t)c * kR + r1) * kCin * kO;
    #pragma unroll
    for (int o = 0; o < kO; ++o) {
      float acc = 0.f;
      #pragma unroll
      for (int i = 0; i < kCin; ++i) acc += xa[i] * Wc[i * kO + o];
      P1[o] = acc;
    }
  }
  if (has2) {
    float xa[kCin];
    #pragma unroll
    for (int i = 0; i < kCin; ++i) xa[i] = xb[i * kR + r2];
    const float* Wc = W + ((size_t)c * kR + r2) * kCin * kO;
    #pragma unroll
    for (int o = 0; o < kO; ++o) {
      float acc = 0.f;
      #pragma unroll
      for (int i = 0; i < kCin; ++i) acc += xa[i] * Wc[i * kO + o];
      P2[o] = acc;
    }
  }

  float l1 = 0.f, l2 = 0.f;
  #pragma unroll
  for (int it = 0; it < NITER; ++it) {
    const float e1 = (it == 0) ? 1.f : __expf(l1);
    const float e2 = has2 ? ((it == 0) ? 1.f : __expf(l2)) : 0.f;
    float sp[kO + 1];
    sp[kO] = e1 + e2;
    #pragma unroll
    for (int o = 0; o < kO; ++o) sp[o] = e1 * P1[o] + e2 * P2[o];
    #pragma unroll
    for (int v = 0; v <= kO; ++v) {
      sp[v] = dpp_xor1_add(sp[v]);
      sp[v] = dpp_xor2_add(sp[v]);
    }
    if ((t & 3) == 0) {
      float* row = &red[(t >> 2) * RST];
      #pragma unroll
      for (int q = 0; q < 4; ++q)
        *reinterpret_cast<float4*>(row + 4 * q) =
            make_float4(sp[4*q], sp[4*q+1], sp[4*q+2], sp[4*q+3]);
      row[16] = sp[16];
    }
    __syncthreads();
    if (t < 136) {
      const int q = t / 17, col = t - q * 17;
      float a = 0.f;
      #pragma unroll
      for (int rr = 0; rr < 16; ++rr) a += red[(rr * 8 + q) * RST + col];
      red2[q * RST + col] = a;
    }
    __syncthreads();
    if (t < 17) {
      float a = 0.f;
      #pragma unroll
      for (int q = 0; q < 8; ++q) a += red2[q * RST + t];
      shs[t] = a;
    }
    __syncthreads();
    const float Zi = 1.f / shs[kO];
    float ss = 0.f;
    #pragma unroll
    for (int o = 0; o < kO; ++o) ss += shs[o] * shs[o];
    const float sn = ss * Zi * Zi;
    const float g  = Zi * sqrtf(sn) / (1.f + sn);
    if (it < NITER - 1) {
      float d1 = 0.f, d2 = 0.f;
      #pragma unroll
      for (int o = 0; o < kO; ++o) { d1 += P1[o] * shs[o]; d2 += P2[o] * shs[o]; }
      l1 += d1 * g;
      if (has2) l2 += d2 * g;
    } else {
      if (t < kO) out[(size_t)b * kO * kNC + t * kNC + c] = shs[t] * g;
    }
  }
}

}  // namespace

extern "C" void kernel_launch(void* const* d_in, const int* in_sizes, int n_in,
                              void* d_out, int out_size, void* d_ws, size_t ws_size,
                              hipStream_t stream) {
  const float* x = (const float*)d_in[0];   // [64, 8, 800] fp32
  const float* W = (const float*)d_in[1];   // [128, 800, 8, 16] fp32
  float* out = (float*)d_out;               // [64, 16, 128] fp32
  (void)in_sizes; (void)n_in; (void)out_size;

  if (ws_size >= WS_NEEDED) {
    unsigned short* Wb = (unsigned short*)d_ws;
    conv_w<<<dim3(kNC * 25), dim3(CT), 0, stream>>>(W, Wb);
    caps_route<<<dim3(kNC * kB / 2), dim3(MT), 0, stream>>>(x, Wb, out);
  } else {
    caps_route_f32<<<dim3(kNC * kB), dim3(MT), 0, stream>>>(x, W, out);
  }
}

// Round 3
// 235.778 us; speedup vs baseline: 1.5626x; 1.5626x over previous
//
#include <hip/hip_runtime.h>
#include <math.h>

namespace {

constexpr int kB   = 64;
constexpr int kCin = 8;
constexpr int kR   = 800;
constexpr int kNC  = 128;
constexpr int kO   = 16;
constexpr int CT   = 256;   // conversion kernel TPB
constexpr int MT   = 512;   // main kernel TPB
constexpr int NITER = 3;
constexpr size_t WS_NEEDED =
    (size_t)kNC * kO * kR * kCin * sizeof(unsigned short);  // 26,214,400 B

typedef _Float16 half2v __attribute__((ext_vector_type(2)));

__device__ __forceinline__ half2v u2h(unsigned int u) {
  union { unsigned int u; half2v h; } x;
  x.u = u;
  return x.h;
}

__device__ __forceinline__ unsigned short f2h(float f) {
  union { _Float16 h; unsigned short s; } x;
  x.h = (_Float16)f;
  return x.s;
}

// DPP adds: xor1 = quad_perm{1,0,3,2}=0xB1, xor2 = quad_perm{2,3,0,1}=0x4E,
// mir8 = row_half_mirror (0x141): lane i <-> 7-i within each 8-lane half-row.
__device__ __forceinline__ float dpp_xor1_add(float v) {
  const int o = __builtin_amdgcn_mov_dpp(__float_as_int(v), 0xB1, 0xF, 0xF, true);
  return v + __int_as_float(o);
}
__device__ __forceinline__ float dpp_xor2_add(float v) {
  const int o = __builtin_amdgcn_mov_dpp(__float_as_int(v), 0x4E, 0xF, 0xF, true);
  return v + __int_as_float(o);
}
__device__ __forceinline__ float dpp_mir8_add(float v) {
  const int o = __builtin_amdgcn_mov_dpp(__float_as_int(v), 0x141, 0xF, 0xF, true);
  return v + __int_as_float(o);
}

// ---- W conversion: fp32 [c][r][i][o] -> fp16 [c][o][r][i] (uint4 = 8 i's) --
// Streaming 32-row tiles: 16.9 KB LDS -> 8 blocks/CU, 3200 blocks.
__global__ __launch_bounds__(CT) void conv_w(const float* __restrict__ W,
                                             unsigned short* __restrict__ Wb) {
  __shared__ float tile[32 * 132];   // 32 r-rows x 128 cols (+4 pad)
  const int blk = blockIdx.x;        // c*25 + rt
  const int c  = blk / 25;
  const int rt = blk - c * 25;
  const int r0 = rt * 32;
  const int t  = threadIdx.x;

  const float4* src =
      reinterpret_cast<const float4*>(W + ((size_t)c * kR + r0) * kCin * kO);
  #pragma unroll
  for (int k2 = 0; k2 < 4; ++k2) {
    const int i4  = t + k2 * CT;
    const float4 v = src[i4];
    const int fi = i4 * 4, row = fi >> 7, pos = fi & 127;
    *reinterpret_cast<float4*>(&tile[row * 132 + pos]) = v;
  }
  __syncthreads();

  const int o = t >> 4;
  #pragma unroll
  for (int k2 = 0; k2 < 2; ++k2) {
    const int rl = (t & 15) + 16 * k2;
    unsigned int pk[4];
    #pragma unroll
    for (int q = 0; q < 4; ++q) {
      const unsigned int lo = f2h(tile[rl * 132 + (2 * q + 0) * 16 + o]);
      const unsigned int hi = f2h(tile[rl * 132 + (2 * q + 1) * 16 + o]);
      pk[q] = lo | (hi << 16);
    }
    reinterpret_cast<uint4*>(Wb)[(size_t)(c * kO + o) * kR + (r0 + rl)] =
        make_uint4(pk[0], pk[1], pk[2], pk[3]);
  }
}

// Per-row prior computation for TWO batches sharing one W load stream.
__device__ __forceinline__ void row_priors(const uint4* __restrict__ Wc,
                                           const float* __restrict__ xb0,
                                           const float* __restrict__ xb1,
                                           int r,
                                           half2v* __restrict__ Pa,
                                           half2v* __restrict__ Pb) {
  half2v xa[4], xc[4];
  #pragma unroll
  for (int q = 0; q < 4; ++q) {
    xa[q] = half2v{(_Float16)xb0[(2*q) * kR + r], (_Float16)xb0[(2*q+1) * kR + r]};
    xc[q] = half2v{(_Float16)xb1[(2*q) * kR + r], (_Float16)xb1[(2*q+1) * kR + r]};
  }
  #pragma unroll
  for (int ob = 0; ob < 2; ++ob) {
    uint4 w[8];
    #pragma unroll
    for (int u = 0; u < 8; ++u) w[u] = Wc[(size_t)(ob * 8 + u) * kR + r];
    float pa[8], pb[8];
    #pragma unroll
    for (int u = 0; u < 8; ++u) {
      float a = __builtin_amdgcn_fdot2(u2h(w[u].x), xa[0], 0.f, false);
      a = __builtin_amdgcn_fdot2(u2h(w[u].y), xa[1], a, false);
      a = __builtin_amdgcn_fdot2(u2h(w[u].z), xa[2], a, false);
      a = __builtin_amdgcn_fdot2(u2h(w[u].w), xa[3], a, false);
      pa[u] = a;
      float bb = __builtin_amdgcn_fdot2(u2h(w[u].x), xc[0], 0.f, false);
      bb = __builtin_amdgcn_fdot2(u2h(w[u].y), xc[1], bb, false);
      bb = __builtin_amdgcn_fdot2(u2h(w[u].z), xc[2], bb, false);
      bb = __builtin_amdgcn_fdot2(u2h(w[u].w), xc[3], bb, false);
      pb[u] = bb;
    }
    #pragma unroll
    for (int q = 0; q < 4; ++q) {
      Pa[ob * 4 + q] = half2v{(_Float16)pa[2*q], (_Float16)pa[2*q+1]};
      Pb[ob * 4 + q] = half2v{(_Float16)pb[2*q], (_Float16)pb[2*q+1]};
    }
  }
}

// ---- main: 2-way b-batching (R2 structure). R3 single change:
// __launch_bounds__(MT, 2) instead of (MT, 4). R2's bound pinned VGPR=64
// (cap = 2048/32 waves) and the doubled prior state spilled ~1 GB of
// scratch (FETCH 468 MB / WRITE 560 MB, dur 292us). Cap 128 removes the
// spill; occupancy ceiling 16 waves/CU = 50% > the 44% actually achieved,
// so no occupancy loss expected. ----
__global__ __launch_bounds__(MT, 2) void caps_route(
    const float* __restrict__ x, const unsigned short* __restrict__ Wb,
    float* __restrict__ out) {
  constexpr int RST = 20;                 // 17 cols + 3 pad
  __shared__ float red[2 * 128 * RST];    // 20.5 KB (b0: rows 0-127, b1: 128-255)
  __shared__ float shs[2 * RST];

  const int t = threadIdx.x;
  // XCD swizzle: 16 c's per XCD -> fp16 W working set 3.3 MB < 4 MB L2.
  const int j   = blockIdx.x;
  const int xcd = j & 7;
  const int kk  = j >> 3;                 // 0..511
  const int c   = ((kk >> 5) << 3) + xcd; // 0..127
  const int bp  = kk & 31;                // 0..31
  const int b0  = 2 * bp, b1 = b0 + 1;

  const float* xb0 = x + (size_t)b0 * kCin * kR;
  const float* xb1 = x + (size_t)b1 * kCin * kR;
  const bool  has2 = (t < kR - MT);       // t < 288 owns second row r2
  const int   r1   = t, r2 = MT + t;

  // Packed priors: P{batch}{row}[8] half2v (16 o's each) = 32 VGPR total.
  half2v P00[8], P01[8], P10[8], P11[8];
  #pragma unroll
  for (int q = 0; q < 8; ++q) {
    P01[q] = half2v{(_Float16)0.f, (_Float16)0.f};
    P11[q] = half2v{(_Float16)0.f, (_Float16)0.f};
  }

  const uint4* Wc = reinterpret_cast<const uint4*>(Wb) + (size_t)c * kO * kR;

  row_priors(Wc, xb0, xb1, r1, P00, P10);
  if (has2) row_priors(Wc, xb0, xb1, r2, P01, P11);

  // -------- Phase 2: 3 routing iterations, both b's concurrent ------------
  float l00 = 0.f, l01 = 0.f, l10 = 0.f, l11 = 0.f;  // l{b}{row}
  #pragma unroll
  for (int it = 0; it < NITER; ++it) {
    const float e00 = (it == 0) ? 1.f : __expf(l00);
    const float e01 = has2 ? ((it == 0) ? 1.f : __expf(l01)) : 0.f;
    const float e10 = (it == 0) ? 1.f : __expf(l10);
    const float e11 = has2 ? ((it == 0) ? 1.f : __expf(l11)) : 0.f;

    float sp0[kO + 1], sp1[kO + 1];
    sp0[kO] = e00 + e01;
    sp1[kO] = e10 + e11;
    #pragma unroll
    for (int q = 0; q < 8; ++q) {
      sp0[2*q]   = e00 * (float)P00[q].x + e01 * (float)P01[q].x;
      sp0[2*q+1] = e00 * (float)P00[q].y + e01 * (float)P01[q].y;
      sp1[2*q]   = e10 * (float)P10[q].x + e11 * (float)P11[q].x;
      sp1[2*q+1] = e10 * (float)P10[q].y + e11 * (float)P11[q].y;
    }

    #pragma unroll
    for (int v = 0; v <= kO; ++v) { sp0[v] = dpp_xor1_add(sp0[v]); sp1[v] = dpp_xor1_add(sp1[v]); }
    #pragma unroll
    for (int v = 0; v <= kO; ++v) { sp0[v] = dpp_xor2_add(sp0[v]); sp1[v] = dpp_xor2_add(sp1[v]); }

    if ((t & 3) == 0) {
      float* ra = &red[(t >> 2) * RST];
      float* rb = &red[(128 + (t >> 2)) * RST];
      #pragma unroll
      for (int q = 0; q < 4; ++q) {
        *reinterpret_cast<float4*>(ra + 4 * q) =
            make_float4(sp0[4*q], sp0[4*q+1], sp0[4*q+2], sp0[4*q+3]);
        *reinterpret_cast<float4*>(rb + 4 * q) =
            make_float4(sp1[4*q], sp1[4*q+1], sp1[4*q+2], sp1[4*q+3]);
      }
      ra[16] = sp0[16];
      rb[16] = sp1[16];
    }
    __syncthreads();

    // Merged stage 2+3: t<136 handles b0, t in [256,392) handles b1.
    // tt = col*8+q: 8-lane DPP group (fixed col) sums the 8 q-partials.
    if (t < 136 || (t >= 256 && t < 392)) {
      const int bsel = t >> 8;            // 0 or 1
      const int tt   = t & 255;           // 0..135
      const int q    = tt & 7, col = tt >> 3;
      const float* base = &red[bsel * 128 * RST];
      float a = 0.f;
      #pragma unroll
      for (int rr = 0; rr < 16; ++rr) a += base[(rr * 8 + q) * RST + col];
      a = dpp_xor1_add(a);
      a = dpp_xor2_add(a);
      a = dpp_mir8_add(a);
      if (q == 0) shs[bsel * RST + col] = a;
    }
    __syncthreads();

    const float Z0i = 1.f / shs[kO];
    const float Z1i = 1.f / shs[RST + kO];
    float ss0 = 0.f, ss1 = 0.f;
    #pragma unroll
    for (int o = 0; o < kO; ++o) {
      ss0 += shs[o] * shs[o];
      ss1 += shs[RST + o] * shs[RST + o];
    }
    const float sn0 = ss0 * Z0i * Z0i;
    const float g0  = Z0i * sqrtf(sn0) / (1.f + sn0);
    const float sn1 = ss1 * Z1i * Z1i;
    const float g1  = Z1i * sqrtf(sn1) / (1.f + sn1);

    if (it < NITER - 1) {
      float d00 = 0.f, d01 = 0.f, d10 = 0.f, d11 = 0.f;
      #pragma unroll
      for (int q = 0; q < 8; ++q) {
        const float s0a = shs[2*q], s0b = shs[2*q+1];
        const float s1a = shs[RST + 2*q], s1b = shs[RST + 2*q+1];
        d00 += (float)P00[q].x * s0a + (float)P00[q].y * s0b;
        d01 += (float)P01[q].x * s0a + (float)P01[q].y * s0b;
        d10 += (float)P10[q].x * s1a + (float)P10[q].y * s1b;
        d11 += (float)P11[q].x * s1a + (float)P11[q].y * s1b;
      }
      l00 += d00 * g0;
      if (has2) l01 += d01 * g0;
      l10 += d10 * g1;
      if (has2) l11 += d11 * g1;
    } else {
      if (t < kO) {
        out[(size_t)b0 * kO * kNC + t * kNC + c] = shs[t] * g0;
      } else if (t >= 256 && t < 256 + kO) {
        const int o = t - 256;
        out[(size_t)b1 * kO * kNC + o * kNC + c] = shs[RST + o] * g1;
      }
    }
  }
}

// ---- fallback (no workspace): fp32 W direct, single-b blocks -------------
__global__ __launch_bounds__(MT, 2) void caps_route_f32(
    const float* __restrict__ x, const float* __restrict__ W,
    float* __restrict__ out) {
  constexpr int RST = 20;
  __shared__ float red[128 * RST];
  __shared__ float red2[8 * RST];
  __shared__ float shs[RST];

  const int t   = threadIdx.x;
  const int j   = blockIdx.x;
  const int xcd = j & 7;
  const int kk  = j >> 3;
  const int c   = ((kk >> 6) << 3) + xcd;
  const int b   = kk & 63;

  const float* xb  = x + (size_t)b * kCin * kR;
  const bool  has2 = (t < kR - MT);
  const int   r1   = t, r2 = MT + t;

  float P1[kO], P2[kO];
  #pragma unroll
  for (int o = 0; o < kO; ++o) P2[o] = 0.f;
  {
    float xa[kCin];
    #pragma unroll
    for (int i = 0; i < kCin; ++i) xa[i] = xb[i * kR + r1];
    const float* Wc = W + ((size_t)c * kR + r1) * kCin * kO;
    #pragma unroll
    for (int o = 0; o < kO; ++o) {
      float acc = 0.f;
      #pragma unroll
      for (int i = 0; i < kCin; ++i) acc += xa[i] * Wc[i * kO + o];
      P1[o] = acc;
    }
  }
  if (has2) {
    float xa[kCin];
    #pragma unroll
    for (int i = 0; i < kCin; ++i) xa[i] = xb[i * kR + r2];
    const float* Wc = W + ((size_t)c * kR + r2) * kCin * kO;
    #pragma unroll
    for (int o = 0; o < kO; ++o) {
      float acc = 0.f;
      #pragma unroll
      for (int i = 0; i < kCin; ++i) acc += xa[i] * Wc[i * kO + o];
      P2[o] = acc;
    }
  }

  float l1 = 0.f, l2 = 0.f;
  #pragma unroll
  for (int it = 0; it < NITER; ++it) {
    const float e1 = (it == 0) ? 1.f : __expf(l1);
    const float e2 = has2 ? ((it == 0) ? 1.f : __expf(l2)) : 0.f;
    float sp[kO + 1];
    sp[kO] = e1 + e2;
    #pragma unroll
    for (int o = 0; o < kO; ++o) sp[o] = e1 * P1[o] + e2 * P2[o];
    #pragma unroll
    for (int v = 0; v <= kO; ++v) {
      sp[v] = dpp_xor1_add(sp[v]);
      sp[v] = dpp_xor2_add(sp[v]);
    }
    if ((t & 3) == 0) {
      float* row = &red[(t >> 2) * RST];
      #pragma unroll
      for (int q = 0; q < 4; ++q)
        *reinterpret_cast<float4*>(row + 4 * q) =
            make_float4(sp[4*q], sp[4*q+1], sp[4*q+2], sp[4*q+3]);
      row[16] = sp[16];
    }
    __syncthreads();
    if (t < 136) {
      const int q = t / 17, col = t - q * 17;
      float a = 0.f;
      #pragma unroll
      for (int rr = 0; rr < 16; ++rr) a += red[(rr * 8 + q) * RST + col];
      red2[q * RST + col] = a;
    }
    __syncthreads();
    if (t < 17) {
      float a = 0.f;
      #pragma unroll
      for (int q = 0; q < 8; ++q) a += red2[q * RST + t];
      shs[t] = a;
    }
    __syncthreads();
    const float Zi = 1.f / shs[kO];
    float ss = 0.f;
    #pragma unroll
    for (int o = 0; o < kO; ++o) ss += shs[o] * shs[o];
    const float sn = ss * Zi * Zi;
    const float g  = Zi * sqrtf(sn) / (1.f + sn);
    if (it < NITER - 1) {
      float d1 = 0.f, d2 = 0.f;
      #pragma unroll
      for (int o = 0; o < kO; ++o) { d1 += P1[o] * shs[o]; d2 += P2[o] * shs[o]; }
      l1 += d1 * g;
      if (has2) l2 += d2 * g;
    } else {
      if (t < kO) out[(size_t)b * kO * kNC + t * kNC + c] = shs[t] * g;
    }
  }
}

}  // namespace

extern "C" void kernel_launch(void* const* d_in, const int* in_sizes, int n_in,
                              void* d_out, int out_size, void* d_ws, size_t ws_size,
                              hipStream_t stream) {
  const float* x = (const float*)d_in[0];   // [64, 8, 800] fp32
  const float* W = (const float*)d_in[1];   // [128, 800, 8, 16] fp32
  float* out = (float*)d_out;               // [64, 16, 128] fp32
  (void)in_sizes; (void)n_in; (void)out_size;

  if (ws_size >= WS_NEEDED) {
    unsigned short* Wb = (unsigned short*)d_ws;
    conv_w<<<dim3(kNC * 25), dim3(CT), 0, stream>>>(W, Wb);
    caps_route<<<dim3(kNC * kB / 2), dim3(MT), 0, stream>>>(x, Wb, out);
  } else {
    caps_route_f32<<<dim3(kNC * kB), dim3(MT), 0, stream>>>(x, W, out);
  }
}

// Round 6
// 201.967 us; speedup vs baseline: 1.8242x; 1.1674x over previous
//
#include <hip/hip_runtime.h>
#include <math.h>

namespace {

constexpr int kB   = 64;
constexpr int kCin = 8;
constexpr int kR   = 800;
constexpr int kNC  = 128;
constexpr int kO   = 16;
constexpr int CT   = 256;   // conversion kernel TPB
constexpr int MT   = 512;   // main kernel TPB
constexpr int NITER = 3;
constexpr size_t WS_NEEDED =
    (size_t)kNC * kO * kR * kCin * sizeof(unsigned short);  // 26,214,400 B

typedef _Float16 half2v __attribute__((ext_vector_type(2)));

__device__ __forceinline__ half2v u2h(unsigned int u) {
  union { unsigned int u; half2v h; } x;
  x.u = u;
  return x.h;
}

__device__ __forceinline__ unsigned short f2h(float f) {
  union { _Float16 h; unsigned short s; } x;
  x.h = (_Float16)f;
  return x.s;
}

// DPP adds: xor1 = quad_perm{1,0,3,2}=0xB1, xor2 = quad_perm{2,3,0,1}=0x4E,
// mir8 = row_half_mirror (0x141): lane i <-> 7-i within each 8-lane half-row.
__device__ __forceinline__ float dpp_xor1_add(float v) {
  const int o = __builtin_amdgcn_mov_dpp(__float_as_int(v), 0xB1, 0xF, 0xF, true);
  return v + __int_as_float(o);
}
__device__ __forceinline__ float dpp_xor2_add(float v) {
  const int o = __builtin_amdgcn_mov_dpp(__float_as_int(v), 0x4E, 0xF, 0xF, true);
  return v + __int_as_float(o);
}
__device__ __forceinline__ float dpp_mir8_add(float v) {
  const int o = __builtin_amdgcn_mov_dpp(__float_as_int(v), 0x141, 0xF, 0xF, true);
  return v + __int_as_float(o);
}

// ---- W conversion: fp32 [c][r][i][o] -> fp16 [c][o][r][i] (uint4 = 8 i's) --
// R1-proven streaming 32-row tiles: 16.9 KB LDS -> 8 blocks/CU, 3200 blocks.
__global__ __launch_bounds__(CT) void conv_w(const float* __restrict__ W,
                                             unsigned short* __restrict__ Wb) {
  __shared__ float tile[32 * 132];   // 32 r-rows x 128 cols (+4 pad)
  const int blk = blockIdx.x;        // c*25 + rt
  const int c  = blk / 25;
  const int rt = blk - c * 25;
  const int r0 = rt * 32;
  const int t  = threadIdx.x;

  const float4* src =
      reinterpret_cast<const float4*>(W + ((size_t)c * kR + r0) * kCin * kO);
  #pragma unroll
  for (int k2 = 0; k2 < 4; ++k2) {
    const int i4  = t + k2 * CT;
    const float4 v = src[i4];
    const int fi = i4 * 4, row = fi >> 7, pos = fi & 127;
    *reinterpret_cast<float4*>(&tile[row * 132 + pos]) = v;
  }
  __syncthreads();

  const int o = t >> 4;
  #pragma unroll
  for (int k2 = 0; k2 < 2; ++k2) {
    const int rl = (t & 15) + 16 * k2;
    unsigned int pk[4];
    #pragma unroll
    for (int q = 0; q < 4; ++q) {
      const unsigned int lo = f2h(tile[rl * 132 + (2 * q + 0) * 16 + o]);
      const unsigned int hi = f2h(tile[rl * 132 + (2 * q + 1) * 16 + o]);
      pk[q] = lo | (hi << 16);
    }
    reinterpret_cast<uint4*>(Wb)[(size_t)(c * kO + o) * kR + (r0 + rl)] =
        make_uint4(pk[0], pk[1], pk[2], pk[3]);
  }
}

// ---- main: EXACT R0 structure (single-b, 8192 blocks, o-paired fp16 P,
// per-iter unpack, 8-deep load chunks, (MT,4), VGPR=64) with ONE swap:
// the R3-proven merged stage-2/3 reduction (stride-8 rows + 8-lane DPP
// xor1/xor2/mir8 finish). 2 barriers/iter instead of 3; bank conflicts
// 1.67M -> 0. R5's fdot2/row-paired-Pi experiment is reverted (it failed
// correctness; bug not identifiable by inspection). ----
__global__ __launch_bounds__(MT, 4) void caps_route(
    const float* __restrict__ x, const unsigned short* __restrict__ Wb,
    float* __restrict__ out) {
  constexpr int RST = 20;               // 17 cols + 3 pad (16B-aligned rows)
  __shared__ float red[128 * RST];      // 10 KB
  __shared__ float shs[RST];

  const int t = threadIdx.x;
  // XCD swizzle: 16 c's per XCD -> fp16 W working set 3.3 MB < 4 MB L2.
  const int j   = blockIdx.x;
  const int xcd = j & 7;
  const int kk  = j >> 3;               // 0..1023
  const int c   = ((kk >> 6) << 3) + xcd;
  const int b   = kk & 63;

  const float* xb  = x + (size_t)b * kCin * kR;
  const bool  has2 = (t < kR - MT);     // t < 288 owns second row r2
  const int   r1   = t, r2 = MT + t;

  // Priors stored packed o-pairs (R0-proven): 8 half2v per row.
  half2v P1[8], P2[8];
  #pragma unroll
  for (int q = 0; q < 8; ++q) P2[q] = half2v{(_Float16)0.f, (_Float16)0.f};

  const uint4* Wc = reinterpret_cast<const uint4*>(Wb) + (size_t)c * kO * kR;

  // -------- Phase 1: fdot2 rows; explicit 8-deep load chunks ----------------
  {
    half2v xp[4];
    #pragma unroll
    for (int q = 0; q < 4; ++q)
      xp[q] = half2v{(_Float16)xb[(2*q) * kR + r1], (_Float16)xb[(2*q+1) * kR + r1]};
    float p[16];
    #pragma unroll
    for (int ob = 0; ob < 2; ++ob) {
      uint4 w[8];
      #pragma unroll
      for (int u = 0; u < 8; ++u) w[u] = Wc[(size_t)(ob * 8 + u) * kR + r1];
      #pragma unroll
      for (int u = 0; u < 8; ++u) {
        float a = __builtin_amdgcn_fdot2(u2h(w[u].x), xp[0], 0.f, false);
        a = __builtin_amdgcn_fdot2(u2h(w[u].y), xp[1], a, false);
        a = __builtin_amdgcn_fdot2(u2h(w[u].z), xp[2], a, false);
        a = __builtin_amdgcn_fdot2(u2h(w[u].w), xp[3], a, false);
        p[ob * 8 + u] = a;
      }
    }
    #pragma unroll
    for (int q = 0; q < 8; ++q)
      P1[q] = half2v{(_Float16)p[2*q], (_Float16)p[2*q+1]};
  }
  if (has2) {
    half2v xp[4];
    #pragma unroll
    for (int q = 0; q < 4; ++q)
      xp[q] = half2v{(_Float16)xb[(2*q) * kR + r2], (_Float16)xb[(2*q+1) * kR + r2]};
    float p[16];
    #pragma unroll
    for (int ob = 0; ob < 2; ++ob) {
      uint4 w[8];
      #pragma unroll
      for (int u = 0; u < 8; ++u) w[u] = Wc[(size_t)(ob * 8 + u) * kR + r2];
      #pragma unroll
      for (int u = 0; u < 8; ++u) {
        float a = __builtin_amdgcn_fdot2(u2h(w[u].x), xp[0], 0.f, false);
        a = __builtin_amdgcn_fdot2(u2h(w[u].y), xp[1], a, false);
        a = __builtin_amdgcn_fdot2(u2h(w[u].z), xp[2], a, false);
        a = __builtin_amdgcn_fdot2(u2h(w[u].w), xp[3], a, false);
        p[ob * 8 + u] = a;
      }
    }
    #pragma unroll
    for (int q = 0; q < 8; ++q)
      P2[q] = half2v{(_Float16)p[2*q], (_Float16)p[2*q+1]};
  }

  // -------- Phase 2: 3 routing iterations (fp32 math; unpack P per iter) ----
  float l1 = 0.f, l2 = 0.f;
  #pragma unroll
  for (int it = 0; it < NITER; ++it) {
    const float e1 = (it == 0) ? 1.f : __expf(l1);
    const float e2 = has2 ? ((it == 0) ? 1.f : __expf(l2)) : 0.f;

    float u1[kO], u2[kO];
    #pragma unroll
    for (int q = 0; q < 8; ++q) {
      u1[2*q]   = (float)P1[q].x; u1[2*q+1] = (float)P1[q].y;
      u2[2*q]   = (float)P2[q].x; u2[2*q+1] = (float)P2[q].y;
    }

    float sp[kO + 1];
    sp[kO] = e1 + e2;
    #pragma unroll
    for (int o = 0; o < kO; ++o) sp[o] = e1 * u1[o] + e2 * u2[o];

    #pragma unroll
    for (int v = 0; v <= kO; ++v) {
      sp[v] = dpp_xor1_add(sp[v]);
      sp[v] = dpp_xor2_add(sp[v]);
    }
    if ((t & 3) == 0) {
      float* row = &red[(t >> 2) * RST];
      #pragma unroll
      for (int q = 0; q < 4; ++q)
        *reinterpret_cast<float4*>(row + 4 * q) =
            make_float4(sp[4*q], sp[4*q+1], sp[4*q+2], sp[4*q+3]);
      row[16] = sp[16];
    }
    __syncthreads();

    // Merged stage 2+3 (R3-proven, zero bank conflicts):
    // t = col*8+q; 8-lane DPP group (fixed col) sums the 8 q-partials.
    if (t < 136) {
      const int q = t & 7, col = t >> 3;
      float a = 0.f;
      #pragma unroll
      for (int rr = 0; rr < 16; ++rr) a += red[(rr * 8 + q) * RST + col];
      a = dpp_xor1_add(a);
      a = dpp_xor2_add(a);
      a = dpp_mir8_add(a);
      if (q == 0) shs[col] = a;
    }
    __syncthreads();

    const float Zi = 1.f / shs[kO];
    float ss = 0.f;
    #pragma unroll
    for (int o = 0; o < kO; ++o) ss += shs[o] * shs[o];
    const float sn = ss * Zi * Zi;
    const float g  = Zi * sqrtf(sn) / (1.f + sn);

    if (it < NITER - 1) {
      float d1 = 0.f, d2 = 0.f;
      #pragma unroll
      for (int o = 0; o < kO; ++o) { d1 += u1[o] * shs[o]; d2 += u2[o] * shs[o]; }
      l1 += d1 * g;
      if (has2) l2 += d2 * g;
    } else {
      if (t < kO) out[(size_t)b * kO * kNC + t * kNC + c] = shs[t] * g;
    }
  }
}

// ---- fallback (no workspace): fp32 W direct ------------------------------
__global__ __launch_bounds__(MT, 4) void caps_route_f32(
    const float* __restrict__ x, const float* __restrict__ W,
    float* __restrict__ out) {
  constexpr int RST = 20;
  __shared__ float red[128 * RST];
  __shared__ float shs[RST];

  const int t   = threadIdx.x;
  const int j   = blockIdx.x;
  const int xcd = j & 7;
  const int kk  = j >> 3;
  const int c   = ((kk >> 6) << 3) + xcd;
  const int b   = kk & 63;

  const float* xb  = x + (size_t)b * kCin * kR;
  const bool  has2 = (t < kR - MT);
  const int   r1   = t, r2 = MT + t;

  float P1[kO], P2[kO];
  #pragma unroll
  for (int o = 0; o < kO; ++o) P2[o] = 0.f;
  {
    float xa[kCin];
    #pragma unroll
    for (int i = 0; i < kCin; ++i) xa[i] = xb[i * kR + r1];
    const float* Wc = W + ((size_t)c * kR + r1) * kCin * kO;
    #pragma unroll
    for (int o = 0; o < kO; ++o) {
      float acc = 0.f;
      #pragma unroll
      for (int i = 0; i < kCin; ++i) acc += xa[i] * Wc[i * kO + o];
      P1[o] = acc;
    }
  }
  if (has2) {
    float xa[kCin];
    #pragma unroll
    for (int i = 0; i < kCin; ++i) xa[i] = xb[i * kR + r2];
    const float* Wc = W + ((size_t)c * kR + r2) * kCin * kO;
    #pragma unroll
    for (int o = 0; o < kO; ++o) {
      float acc = 0.f;
      #pragma unroll
      for (int i = 0; i < kCin; ++i) acc += xa[i] * Wc[i * kO + o];
      P2[o] = acc;
    }
  }

  float l1 = 0.f, l2 = 0.f;
  #pragma unroll
  for (int it = 0; it < NITER; ++it) {
    const float e1 = (it == 0) ? 1.f : __expf(l1);
    const float e2 = has2 ? ((it == 0) ? 1.f : __expf(l2)) : 0.f;
    float sp[kO + 1];
    sp[kO] = e1 + e2;
    #pragma unroll
    for (int o = 0; o < kO; ++o) sp[o] = e1 * P1[o] + e2 * P2[o];
    #pragma unroll
    for (int v = 0; v <= kO; ++v) {
      sp[v] = dpp_xor1_add(sp[v]);
      sp[v] = dpp_xor2_add(sp[v]);
    }
    if ((t & 3) == 0) {
      float* row = &red[(t >> 2) * RST];
      #pragma unroll
      for (int q = 0; q < 4; ++q)
        *reinterpret_cast<float4*>(row + 4 * q) =
            make_float4(sp[4*q], sp[4*q+1], sp[4*q+2], sp[4*q+3]);
      row[16] = sp[16];
    }
    __syncthreads();
    if (t < 136) {
      const int q = t & 7, col = t >> 3;
      float a = 0.f;
      #pragma unroll
      for (int rr = 0; rr < 16; ++rr) a += red[(rr * 8 + q) * RST + col];
      a = dpp_xor1_add(a);
      a = dpp_xor2_add(a);
      a = dpp_mir8_add(a);
      if (q == 0) shs[col] = a;
    }
    __syncthreads();
    const float Zi = 1.f / shs[kO];
    float ss = 0.f;
    #pragma unroll
    for (int o = 0; o < kO; ++o) ss += shs[o] * shs[o];
    const float sn = ss * Zi * Zi;
    const float g  = Zi * sqrtf(sn) / (1.f + sn);
    if (it < NITER - 1) {
      float d1 = 0.f, d2 = 0.f;
      #pragma unroll
      for (int o = 0; o < kO; ++o) { d1 += P1[o] * shs[o]; d2 += P2[o] * shs[o]; }
      l1 += d1 * g;
      if (has2) l2 += d2 * g;
    } else {
      if (t < kO) out[(size_t)b * kO * kNC + t * kNC + c] = shs[t] * g;
    }
  }
}

}  // namespace

extern "C" void kernel_launch(void* const* d_in, const int* in_sizes, int n_in,
                              void* d_out, int out_size, void* d_ws, size_t ws_size,
                              hipStream_t stream) {
  const float* x = (const float*)d_in[0];   // [64, 8, 800] fp32
  const float* W = (const float*)d_in[1];   // [128, 800, 8, 16] fp32
  float* out = (float*)d_out;               // [64, 16, 128] fp32
  (void)in_sizes; (void)n_in; (void)out_size;

  if (ws_size >= WS_NEEDED) {
    unsigned short* Wb = (unsigned short*)d_ws;
    conv_w<<<dim3(kNC * 25), dim3(CT), 0, stream>>>(W, Wb);
    caps_route<<<dim3(kNC * kB), dim3(MT), 0, stream>>>(x, Wb, out);
  } else {
    caps_route_f32<<<dim3(kNC * kB), dim3(MT), 0, stream>>>(x, W, out);
  }
}